// Round 11
// baseline (207.744 us; speedup 1.0000x reference)
//
#include <hip/hip_runtime.h>

// out[n, mu, mup] = sum_{(m1,m2)∈T(mu)} sum_{(m1p,m2p)∈T(mup)}
//     c_p*c_q * X1[n,m1,m1p] * X2[n,m2,m2p],   T(mu)={m1+m2==mu+4}
// Rank-1 weights: cs[p]*w0[q] = c_p*c_q with w0[q]=mult[q], cs[p]=mult[p]/mult[0].
//
// R11: R10 (~23us) is LDS-read-amplification-bound: x1/x2 rows re-read by up
// to 9 mu-waves per block (1098 b32 reads for 18 rows of data, 6.8x amp,
// ~11us of LDS pipe). Fix: 2 mu per wave (5 waves/block):
//  - x1 row m1 shared by both mu-pairs at that m1 -> read once.
//  - x2 rows for the two pairs are consecutive, and roll by 1 across m1 ->
//    rolling 2-row register buffer, ONE new x2 row per m1 step.
//  - per-block LDS reads 1098 -> 630. acc = 18/lane (~70 VGPR, no spill).
//  - stores: 18 contiguous floats/thread (mu0,mu1 rows adjacent).
// Keep: [c][n] pitch-65 LDS, SGPR w0 (const-indexed), csh LDS scale table,
// one barrier, direct stores.

namespace {

struct QTab {
  int m1p[61];
  int m2p[61];
  int mup[61];
  constexpr QTab() : m1p{}, m2p{}, mup{} {
    int idx = 0;
    for (int mu = 0; mu < 9; ++mu)
      for (int a = 0; a < 9; ++a) {
        int b = mu + 4 - a;
        if (b >= 0 && b < 9) {
          m1p[idx] = a; m2p[idx] = b; mup[idx] = mu; ++idx;
        }
      }
  }
};
constexpr QTab QT{};

// pairs per mu: [5,6,7,8,9,8,7,6,5]
constexpr int kPrefixC[9] = {0, 5, 11, 18, 26, 35, 43, 50, 56};
constexpr int m1loC(int mu) { return mu - 4 > 0 ? mu - 4 : 0; }

}  // namespace

__device__ __forceinline__ float uniform_f32(float v) {
  return __int_as_float(__builtin_amdgcn_readfirstlane(__float_as_int(v)));
}

#define NB 64            // n per block
#define NT 320           // threads = 5 waves (wave w -> mu {2w, 2w+1})
#define PITCH 65         // LDS n-pitch (odd -> near-zero conflicts, measured)
#define ELEMS (NB * 81)  // 5184 floats per array per block
#define NF2 (ELEMS / 2)  // 2592 float2 per array per block

template <int W>
__device__ __forceinline__ void compute_wave(
    const float* __restrict__ x1s, const float* __restrict__ x2s,
    const float* __restrict__ csh, const float (&w0)[61], int lane,
    float* __restrict__ out, long nglob, int N) {
  constexpr int MU0 = 2 * W;
  constexpr bool HAS1 = (W < 4);
  constexpr int MU1 = HAS1 ? (2 * W + 1) : MU0;

  float acc0[9], acc1[9];
#pragma unroll
  for (int j = 0; j < 9; ++j) { acc0[j] = 0.0f; acc1[j] = 0.0f; }

  float x2a[9];  // row MU1+4-m1 (valid when u1)
  float x2b[9];  // row MU0+4-m1 (valid when u0)

#pragma unroll
  for (int m1 = 0; m1 < 9; ++m1) {
    const int M2_0 = MU0 + 4 - m1;   // folds to constant per unrolled body
    const int M2_1 = M2_0 + 1;
    const bool u0 = (M2_0 >= 0 && M2_0 <= 8);
    const bool u1 = HAS1 && (M2_1 >= 0 && M2_1 <= 8);
    if (!u0 && !u1) continue;

    float x1r[9];
#pragma unroll
    for (int j = 0; j < 9; ++j) x1r[j] = x1s[(m1 * 9 + j) * PITCH + lane];

    if (u1) {
      if (m1 == 0) {
        // only the first iteration must load the upper row explicitly;
        // afterwards prev x2b (row M2_0(m1-1) == M2_1) is always valid.
#pragma unroll
        for (int j = 0; j < 9; ++j) x2a[j] = x2s[(M2_1 * 9 + j) * PITCH + lane];
      } else {
#pragma unroll
        for (int j = 0; j < 9; ++j) x2a[j] = x2b[j];  // SSA copy, no movs
      }
    }
    if (u0) {
#pragma unroll
      for (int j = 0; j < 9; ++j) x2b[j] = x2s[(M2_0 * 9 + j) * PITCH + lane];
    }

    if (u0) {
      const int p = kPrefixC[MU0] + (m1 - m1loC(MU0));  // constant
      const float sp = csh[p];                          // uniform ds_read
      float x1w[9];
#pragma unroll
      for (int j = 0; j < 9; ++j) x1w[j] = x1r[j] * sp;
#pragma unroll
      for (int q = 0; q < 61; ++q)
        acc0[QT.mup[q]] = fmaf(w0[q], x1w[QT.m1p[q]] * x2b[QT.m2p[q]],
                               acc0[QT.mup[q]]);
    }
    if (u1) {
      const int p = kPrefixC[MU1] + (m1 - m1loC(MU1));  // constant
      const float sp = csh[p];
      float x1w[9];
#pragma unroll
      for (int j = 0; j < 9; ++j) x1w[j] = x1r[j] * sp;
#pragma unroll
      for (int q = 0; q < 61; ++q)
        acc1[QT.mup[q]] = fmaf(w0[q], x1w[QT.m1p[q]] * x2a[QT.m2p[q]],
                               acc1[QT.mup[q]]);
    }
  }

  if (nglob < N) {
    float* __restrict__ op = out + nglob * 81 + MU0 * 9;
#pragma unroll
    for (int j = 0; j < 9; ++j) op[j] = acc0[j];
    if (HAS1) {
#pragma unroll
      for (int j = 0; j < 9; ++j) op[9 + j] = acc1[j];
    }
  }
}

__global__ __launch_bounds__(NT)
void wigner_combine_kernel(const float* __restrict__ X1,
                           const float* __restrict__ X2,
                           const float* __restrict__ mult,
                           float* __restrict__ out, int N) {
  __shared__ float x1s[81 * PITCH];  // 21060 B
  __shared__ float x2s[81 * PITCH];  // 21060 B
  __shared__ float csh[61];          // per-pair scales c_p / c_p0

  const int t = threadIdx.x;
  const int base = blockIdx.x * ELEMS;
  const long total2 = (long)N * 81 / 2;

  // weight row 0 -> SGPRs (constant indices only)
  float w0[61];
#pragma unroll
  for (int q = 0; q < 61; ++q) w0[q] = uniform_f32(mult[q]);

  if (t < 61) csh[t] = mult[t] * (1.0f / mult[0]);

  // stage: coalesced float2 loads, transposed b32 LDS writes
  const float2* __restrict__ X1v = (const float2*)X1;
  const float2* __restrict__ X2v = (const float2*)X2;
  const long fbase = (long)base / 2;
#pragma unroll
  for (int j = 0; j < 9; ++j) {
    const int f = t + j * NT;
    if (f < NF2) {
      const long gf = fbase + f;
      float2 v1 = make_float2(0.f, 0.f), v2 = make_float2(0.f, 0.f);
      if (gf < total2) { v1 = X1v[gf]; v2 = X2v[gf]; }
      const int e = 2 * f;
      const int n = e / 81;
      const int c = e - n * 81;
      int n2 = n, c2 = c + 1;
      if (c2 == 81) { c2 = 0; n2 = n + 1; }
      x1s[c * PITCH + n] = v1.x;
      x2s[c * PITCH + n] = v2.x;
      if (n2 < NB) {
        x1s[c2 * PITCH + n2] = v1.y;
        x2s[c2 * PITCH + n2] = v2.y;
      }
    }
  }
  __syncthreads();

  const int w = __builtin_amdgcn_readfirstlane(t >> 6);  // wave id 0..4
  const int lane = t & 63;
  const long nglob = (long)blockIdx.x * NB + lane;

  switch (w) {
    case 0: compute_wave<0>(x1s, x2s, csh, w0, lane, out, nglob, N); break;
    case 1: compute_wave<1>(x1s, x2s, csh, w0, lane, out, nglob, N); break;
    case 2: compute_wave<2>(x1s, x2s, csh, w0, lane, out, nglob, N); break;
    case 3: compute_wave<3>(x1s, x2s, csh, w0, lane, out, nglob, N); break;
    case 4: compute_wave<4>(x1s, x2s, csh, w0, lane, out, nglob, N); break;
  }
}

extern "C" void kernel_launch(void* const* d_in, const int* in_sizes, int n_in,
                              void* d_out, int out_size, void* d_ws, size_t ws_size,
                              hipStream_t stream) {
  const float* X1 = (const float*)d_in[0];
  const float* X2 = (const float*)d_in[1];
  const float* mult = (const float*)d_in[6];
  float* out = (float*)d_out;

  const int N = in_sizes[0] / 81;
  const int blocks = (N + NB - 1) / NB;
  wigner_combine_kernel<<<blocks, NT, 0, stream>>>(X1, X2, mult, out, N);
}

// Round 12
// 112.814 us; speedup vs baseline: 1.8415x; 1.8415x over previous
//
#include <hip/hip_runtime.h>

// out[n, mu, mup] = sum_{(m1,m2)∈T(mu)} sum_{(m1p,m2p)∈T(mup)}
//     c_p*c_q * X1[n,m1,m1p] * X2[n,m2,m2p],   T(mu)={m1+m2==mu+4}
// Rank-1 weights: cs[p]*w0[q] = c_p*c_q, w0[q]=mult[q], cs[p]=mult[p]/mult[0].
//
// R12 = R10 (best measured, ~23us) + ONE change: LDS layout [n][9 rows x 12]
// with n-pitch 108 dwords, rows read as 2x ds_read_b128 + 1x b32 (6 instrs
// vs 18 per pair). b128 bank math: lane base bank 12i mod 32, i=0..7 ->
// {0,12,24,4,16,28,8,20} x 4 consecutive dwords = all 32 banks exactly once
// per 8-lane group -> conflict-free at the 128B/clk data limit. (R5's pitch
// 108 failure was b32-access aliasing — different width, different rule.)
// Cost: 55.6 KB LDS -> 2 blocks/CU (18 waves vs 27); LDS issue count -3x.
//
// HARD RULES (learned R6/R8/R11): w0[61] lives INLINE in the kernel body,
// only compile-time indices, never passed by ref / address taken -> SGPRs.
// Per-pair scale from csh[] LDS table (uniform ds_read broadcast, in-order).

namespace {

struct QTab {
  int m1p[61];
  int m2p[61];
  int mup[61];
  constexpr QTab() : m1p{}, m2p{}, mup{} {
    int idx = 0;
    for (int mu = 0; mu < 9; ++mu)
      for (int a = 0; a < 9; ++a) {
        int b = mu + 4 - a;
        if (b >= 0 && b < 9) {
          m1p[idx] = a; m2p[idx] = b; mup[idx] = mu; ++idx;
        }
      }
  }
};
constexpr QTab QT{};

}  // namespace

// pairs per mu: [5,6,7,8,9,8,7,6,5]; prefix = first pair index of each mu
__constant__ __device__ int kPrefix[9] = {0, 5, 11, 18, 26, 35, 43, 50, 56};

__device__ __forceinline__ float uniform_f32(float v) {
  return __int_as_float(__builtin_amdgcn_readfirstlane(__float_as_int(v)));
}

#define NB 64            // n per block
#define NT 576           // threads = 9 waves (wave = mu, lane = n-local)
#define RP 12            // dwords per row (9 used + 3 pad; 16B-aligned rows)
#define NP 108           // dwords per n (9*RP); 108 mod 8 == 4 -> b128 ok
#define ELEMS (NB * 81)  // 5184 floats per array per block
#define NF2 (ELEMS / 2)  // 2592 float2 per array per block

__global__ __launch_bounds__(NT)
void wigner_combine_kernel(const float* __restrict__ X1,
                           const float* __restrict__ X2,
                           const float* __restrict__ mult,
                           float* __restrict__ out, int N) {
  __shared__ __align__(16) float x1s[NB * NP];  // 27648 B
  __shared__ __align__(16) float x2s[NB * NP];  // 27648 B
  __shared__ float csh[61];                     // per-pair scales c_p/c_p0

  const int t = threadIdx.x;
  const int base = blockIdx.x * ELEMS;
  const long total2 = (long)N * 81 / 2;

  // ---- weight row 0 -> 61 SGPRs (inline, constant indices ONLY) ----
  float w0[61];
#pragma unroll
  for (int q = 0; q < 61; ++q) w0[q] = uniform_f32(mult[q]);

  if (t < 61) csh[t] = mult[t] * (1.0f / mult[0]);

  // ---- stage: coalesced float2 loads, b32 writes into [n][row12] ----
  const float2* __restrict__ X1v = (const float2*)X1;
  const float2* __restrict__ X2v = (const float2*)X2;
  const long fbase = (long)base / 2;
#pragma unroll
  for (int j = 0; j < 5; ++j) {
    const int f = t + j * NT;  // local float2 index
    if (f < NF2) {
      const long gf = fbase + f;
      float2 v1 = make_float2(0.f, 0.f), v2 = make_float2(0.f, 0.f);
      if (gf < total2) { v1 = X1v[gf]; v2 = X2v[gf]; }
      const int e = 2 * f;
      const int n = e / 81;
      const int c = e - n * 81;
      const int m = c / 9;
      const int jj = c - m * 9;
      const int a0 = n * NP + m * RP + jj;
      x1s[a0] = v1.x;
      x2s[a0] = v2.x;
      // element e+1: next component (may roll to next row / next n)
      int n2 = n, m2 = m, jj2 = jj + 1;
      if (jj2 == 9) { jj2 = 0; ++m2; }
      if (m2 == 9) { m2 = 0; ++n2; }
      if (n2 < NB) {
        const int a1 = n2 * NP + m2 * RP + jj2;
        x1s[a1] = v1.y;
        x2s[a1] = v2.y;
      }
    }
  }
  __syncthreads();

  // ---- compute: wave = mu, lane = local n ----
  const int mu = __builtin_amdgcn_readfirstlane(t >> 6);  // wave-uniform
  const int lane = t & 63;
  const int m1lo = (mu - 4 > 0) ? mu - 4 : 0;
  const int pbase = kPrefix[mu];

  const float* __restrict__ lx1 = x1s + lane * NP;
  const float* __restrict__ lx2 = x2s + lane * NP;

  float acc[9];
#pragma unroll
  for (int j = 0; j < 9; ++j) acc[j] = 0.0f;

#pragma unroll
  for (int m1 = 0; m1 < 9; ++m1) {
    const int m2 = mu + 4 - m1;      // wave-uniform scalar
    if (m2 < 0 || m2 > 8) continue;  // uniform guard (scalar branch)
    const int p = pbase + (m1 - m1lo);
    const float sp = csh[p];         // uniform ds_read broadcast, in-order

    // row reads: 2x ds_read_b128 + 1x ds_read_b32 each (16B-aligned)
    const float* r1 = lx1 + m1 * RP;
    const float* r2 = lx2 + m2 * RP;
    const float4 a0 = ((const float4*)r1)[0];
    const float4 a1 = ((const float4*)r1)[1];
    const float  a2 = r1[8];
    const float4 b0 = ((const float4*)r2)[0];
    const float4 b1 = ((const float4*)r2)[1];
    const float  b2 = r2[8];
    const float x2r[9] = {b0.x, b0.y, b0.z, b0.w, b1.x, b1.y, b1.z, b1.w, b2};
    const float x1w[9] = {a0.x * sp, a0.y * sp, a0.z * sp, a0.w * sp,
                          a1.x * sp, a1.y * sp, a1.z * sp, a1.w * sp,
                          a2 * sp};

#pragma unroll
    for (int q = 0; q < 61; ++q) {
      // weight = sp * w0[q] = c_p * c_q; w0 const-indexed (SGPRs)
      acc[QT.mup[q]] = fmaf(w0[q], x1w[QT.m1p[q]] * x2r[QT.m2p[q]],
                            acc[QT.mup[q]]);
    }
  }

  // ---- direct stores: out[n, mu, 0..8] (scattered; L2 merges) ----
  const long n = (long)blockIdx.x * NB + lane;
  if (n < N) {
    float* __restrict__ op = out + n * 81 + mu * 9;
#pragma unroll
    for (int j = 0; j < 9; ++j) op[j] = acc[j];
  }
}

extern "C" void kernel_launch(void* const* d_in, const int* in_sizes, int n_in,
                              void* d_out, int out_size, void* d_ws, size_t ws_size,
                              hipStream_t stream) {
  const float* X1 = (const float*)d_in[0];
  const float* X2 = (const float*)d_in[1];
  const float* mult = (const float*)d_in[6];
  float* out = (float*)d_out;

  const int N = in_sizes[0] / 81;
  const int blocks = (N + NB - 1) / NB;
  wigner_combine_kernel<<<blocks, NT, 0, stream>>>(X1, X2, mult, out, N);
}

// Round 13
// 106.304 us; speedup vs baseline: 1.9542x; 1.0612x over previous
//
#include <hip/hip_runtime.h>

// out[n, mu, mup] = sum_{(m1,m2)∈T(mu)} sum_{(m1p,m2p)∈T(mup)}
//     c_p*c_q * X1[n,m1,m1p] * X2[n,m2,m2p],   T(mu)={m1+m2==mu+4}
// Rank-1 weights: cs[p]*w0[q] = c_p*c_q, w0[q]=mult[q], cs[p]=mult[p]/mult[0].
//
// R13 = R10 (best, ~23us; latency-bound at 27 waves/CU — R12 proved dropping
// occupancy loses even with 3x fewer LDS instrs) + LDS layout that cuts
// compute reads 18 -> 10 per pair at UNCHANGED occupancy:
//   rows padded 9 -> 10 components, pair-interleaved, pair stride 130 dwords:
//     addr(n, m, j) = (m*5 + j/2)*130 + 2n + (j&1)
//   - staging writes: bank = (c + 2n) mod 32 -> consecutive threads ->
//     consecutive banks -> conflict-free.
//   - compute row read = 4x ds_read_b64 + 1x b32; lane stride 2 dwords ->
//     2-way aliasing = free (m136). Pattern compile-time for every m1/m2
//     because the 10-pad fixes row parity.
//   - 47.0 KB/block -> still 3 blocks/CU = 27 waves (same as R10).
// HARD RULES (R6/R8/R11): w0[61] inline, const-indexed only, never passed
// or address-taken. No runtime-indexed register arrays anywhere.

namespace {

struct QTab {
  int m1p[61];
  int m2p[61];
  int mup[61];
  constexpr QTab() : m1p{}, m2p{}, mup{} {
    int idx = 0;
    for (int mu = 0; mu < 9; ++mu)
      for (int a = 0; a < 9; ++a) {
        int b = mu + 4 - a;
        if (b >= 0 && b < 9) {
          m1p[idx] = a; m2p[idx] = b; mup[idx] = mu; ++idx;
        }
      }
  }
};
constexpr QTab QT{};

}  // namespace

// pairs per mu: [5,6,7,8,9,8,7,6,5]; prefix = first pair index of each mu
__constant__ __device__ int kPrefix[9] = {0, 5, 11, 18, 26, 35, 43, 50, 56};

__device__ __forceinline__ float uniform_f32(float v) {
  return __int_as_float(__builtin_amdgcn_readfirstlane(__float_as_int(v)));
}

#define NB 64             // n per block
#define NT 576            // threads = 9 waves (wave = mu, lane = n-local)
#define PSTRIDE 130       // dwords per pair-block (2*NB + 2 -> bank c+2n)
#define ROWP (5 * PSTRIDE)  // 650 dwords per padded row
#define AWORDS (9 * ROWP)   // 5850 dwords per array
#define ELEMS (NB * 81)   // 5184 floats per array per block

__global__ __launch_bounds__(NT)
void wigner_combine_kernel(const float* __restrict__ X1,
                           const float* __restrict__ X2,
                           const float* __restrict__ mult,
                           float* __restrict__ out, int N) {
  __shared__ __align__(16) float x1s[AWORDS];  // 23400 B
  __shared__ __align__(16) float x2s[AWORDS];  // 23400 B
  __shared__ float csh[61];                    // per-pair scales c_p/c_p0

  const int t = threadIdx.x;
  const int base = blockIdx.x * ELEMS;
  const long total = (long)N * 81;

  // ---- weight row 0 -> 61 SGPRs (inline, constant indices ONLY) ----
  float w0[61];
#pragma unroll
  for (int q = 0; q < 61; ++q) w0[q] = uniform_f32(mult[q]);

  if (t < 61) csh[t] = mult[t] * (1.0f / mult[0]);

  // ---- stage: coalesced b32 global loads, pair-interleaved LDS writes ----
  // addr(c, n) = (m*5 + jj/2)*130 + 2n + (jj&1); bank = (c + 2n) mod 32
#pragma unroll
  for (int j = 0; j < 9; ++j) {
    const int e = t + j * NT;  // 0..5183 exactly (9*576 == 5184)
    const int n = e / 81;      // magic-div
    const int c = e - n * 81;
    const int m = c / 9;
    const int jj = c - m * 9;
    const long ge = base + e;
    float v1 = 0.0f, v2 = 0.0f;
    if (ge < total) { v1 = X1[ge]; v2 = X2[ge]; }
    const int a = (m * 5 + (jj >> 1)) * PSTRIDE + 2 * n + (jj & 1);
    x1s[a] = v1;
    x2s[a] = v2;
  }
  __syncthreads();

  // ---- compute: wave = mu, lane = local n ----
  const int mu = __builtin_amdgcn_readfirstlane(t >> 6);  // wave-uniform
  const int lane = t & 63;
  const int m1lo = (mu - 4 > 0) ? mu - 4 : 0;
  const int pbase = kPrefix[mu];

  const float* __restrict__ lx1 = x1s + 2 * lane;
  const float* __restrict__ lx2 = x2s + 2 * lane;

  float acc[9];
#pragma unroll
  for (int j = 0; j < 9; ++j) acc[j] = 0.0f;

#pragma unroll
  for (int m1 = 0; m1 < 9; ++m1) {
    const int m2 = mu + 4 - m1;      // wave-uniform scalar
    if (m2 < 0 || m2 > 8) continue;  // uniform guard (scalar branch)
    const int p = pbase + (m1 - m1lo);
    const float sp = csh[p];         // uniform ds_read broadcast, in-order

    // x1 row m1: compile-time offsets -> 4x ds_read_b64 + 1x b32
    const float2 a01 = *(const float2*)(lx1 + m1 * ROWP + 0 * PSTRIDE);
    const float2 a23 = *(const float2*)(lx1 + m1 * ROWP + 1 * PSTRIDE);
    const float2 a45 = *(const float2*)(lx1 + m1 * ROWP + 2 * PSTRIDE);
    const float2 a67 = *(const float2*)(lx1 + m1 * ROWP + 3 * PSTRIDE);
    const float  a8  = *(lx1 + m1 * ROWP + 4 * PSTRIDE);
    // x2 row m2: scalar row base + compile-time pair offsets
    const float* r2 = lx2 + m2 * ROWP;
    const float2 b01 = *(const float2*)(r2 + 0 * PSTRIDE);
    const float2 b23 = *(const float2*)(r2 + 1 * PSTRIDE);
    const float2 b45 = *(const float2*)(r2 + 2 * PSTRIDE);
    const float2 b67 = *(const float2*)(r2 + 3 * PSTRIDE);
    const float  b8  = *(r2 + 4 * PSTRIDE);

    const float x2r[9] = {b01.x, b01.y, b23.x, b23.y,
                          b45.x, b45.y, b67.x, b67.y, b8};
    const float x1w[9] = {a01.x * sp, a01.y * sp, a23.x * sp, a23.y * sp,
                          a45.x * sp, a45.y * sp, a67.x * sp, a67.y * sp,
                          a8 * sp};

#pragma unroll
    for (int q = 0; q < 61; ++q) {
      // weight = sp * w0[q] = c_p * c_q; w0 const-indexed (SGPRs)
      acc[QT.mup[q]] = fmaf(w0[q], x1w[QT.m1p[q]] * x2r[QT.m2p[q]],
                            acc[QT.mup[q]]);
    }
  }

  // ---- direct stores: out[n, mu, 0..8] (scattered; L2 merges) ----
  const long n = (long)blockIdx.x * NB + lane;
  if (n < N) {
    float* __restrict__ op = out + n * 81 + mu * 9;
#pragma unroll
    for (int j = 0; j < 9; ++j) op[j] = acc[j];
  }
}

extern "C" void kernel_launch(void* const* d_in, const int* in_sizes, int n_in,
                              void* d_out, int out_size, void* d_ws, size_t ws_size,
                              hipStream_t stream) {
  const float* X1 = (const float*)d_in[0];
  const float* X2 = (const float*)d_in[1];
  const float* mult = (const float*)d_in[6];
  float* out = (float*)d_out;

  const int N = in_sizes[0] / 81;
  const int blocks = (N + NB - 1) / NB;
  wigner_combine_kernel<<<blocks, NT, 0, stream>>>(X1, X2, mult, out, N);
}

// Round 14
// 103.968 us; speedup vs baseline: 1.9981x; 1.0225x over previous
//
#include <hip/hip_runtime.h>

// out[n, mu, mup] = sum_{(m1,m2)∈T(mu)} sum_{(m1p,m2p)∈T(mup)}
//     c_p*c_q * X1[n,m1,m1p] * X2[n,m2,m2p],   T(mu)={m1+m2==mu+4}
// Rank-1 weights: cs[p]*w0[q] = c_p*c_q, w0[q]=mult[q], cs[p]=mult[p]/mult[0].
//
// R14 = R10 (best, ~23us) + intra-block fetch/compute overlap. Model fitting
// R10-R13: single resident generation (27.5 waves/CU total) -> phases are
// serial: fetch (>=5.1us) -> barrier -> LDS/VALU compute (~10us) -> store.
// LDS-instr cuts (R12/R13) lost because phasing, not pipe, binds. Fix: each
// block does TWO 64-n chunks with one LDS buffer:
//   stage A ; sync ; issue B global loads -> 20 VGPRs ; compute+store A
//   (B in flight; no barrier inside) ; sync (vmcnt(0) drains B exactly when
//   needed) ; write B->LDS ; sync ; compute+store B.
// Occupancy unchanged (42.1 KB, 3 blk/CU, 27 waves). Grid halves -> half the
// w0 preamble. Compute body = R10 verbatim via macro (HARD RULES R6/R8/R11:
// w0 inline, const-indexed, never passed/addressed; no runtime-indexed
// register arrays).

namespace {

struct QTab {
  int m1p[61];
  int m2p[61];
  int mup[61];
  constexpr QTab() : m1p{}, m2p{}, mup{} {
    int idx = 0;
    for (int mu = 0; mu < 9; ++mu)
      for (int a = 0; a < 9; ++a) {
        int b = mu + 4 - a;
        if (b >= 0 && b < 9) {
          m1p[idx] = a; m2p[idx] = b; mup[idx] = mu; ++idx;
        }
      }
  }
};
constexpr QTab QT{};

}  // namespace

// pairs per mu: [5,6,7,8,9,8,7,6,5]; prefix = first pair index of each mu
__constant__ __device__ int kPrefix[9] = {0, 5, 11, 18, 26, 35, 43, 50, 56};

__device__ __forceinline__ float uniform_f32(float v) {
  return __int_as_float(__builtin_amdgcn_readfirstlane(__float_as_int(v)));
}

#define NB 64            // n per chunk
#define NT 576           // threads = 9 waves (wave = mu, lane = n-local)
#define PITCH 65         // LDS n-pitch (odd -> measured conflict-free)
#define ELEMS (NB * 81)  // 5184 floats per array per chunk
#define NF2 (ELEMS / 2)  // 2592 float2 per array per chunk

// Write one float2 pair (elements e = 2f, 2f+1) into the [c][n] LDS layout.
#define LDS_WRITE_PAIR(f, v1, v2)                  \
  {                                                \
    const int e = 2 * (f);                         \
    const int n = e / 81;                          \
    const int c = e - n * 81;                      \
    int n2 = n, c2 = c + 1;                        \
    if (c2 == 81) { c2 = 0; n2 = n + 1; }          \
    x1s[c * PITCH + n] = (v1).x;                   \
    x2s[c * PITCH + n] = (v2).x;                   \
    if (n2 < NB) {                                 \
      x1s[c2 * PITCH + n2] = (v1).y;               \
      x2s[c2 * PITCH + n2] = (v2).y;               \
    }                                              \
  }

// R10's compute body + direct store, for the chunk whose data is in LDS.
#define COMPUTE_AND_STORE(nglob)                                              \
  {                                                                           \
    float acc[9];                                                             \
    _Pragma("unroll") for (int j = 0; j < 9; ++j) acc[j] = 0.0f;              \
    _Pragma("unroll") for (int m1 = 0; m1 < 9; ++m1) {                        \
      const int m2 = mu + 4 - m1;      /* wave-uniform scalar */              \
      if (m2 >= 0 && m2 <= 8) {        /* uniform guard */                    \
        const int p = pbase + (m1 - m1lo);                                    \
        const float sp = csh[p];       /* uniform ds_read broadcast */        \
        float x1w[9], x2r[9];                                                 \
        _Pragma("unroll") for (int j = 0; j < 9; ++j)                         \
            x1w[j] = x1s[(m1 * 9 + j) * PITCH + lane] * sp;                   \
        _Pragma("unroll") for (int j = 0; j < 9; ++j)                         \
            x2r[j] = x2s[(m2 * 9 + j) * PITCH + lane];                        \
        _Pragma("unroll") for (int q = 0; q < 61; ++q)                        \
            acc[QT.mup[q]] = fmaf(w0[q], x1w[QT.m1p[q]] * x2r[QT.m2p[q]],     \
                                  acc[QT.mup[q]]);                            \
      }                                                                       \
    }                                                                         \
    if ((nglob) < N) {                                                        \
      float* __restrict__ op = out + (long)(nglob)*81 + mu * 9;               \
      _Pragma("unroll") for (int j = 0; j < 9; ++j) op[j] = acc[j];           \
    }                                                                         \
  }

__global__ __launch_bounds__(NT)
void wigner_combine_kernel(const float* __restrict__ X1,
                           const float* __restrict__ X2,
                           const float* __restrict__ mult,
                           float* __restrict__ out, int N) {
  __shared__ float x1s[81 * PITCH];  // 21060 B
  __shared__ float x2s[81 * PITCH];  // 21060 B
  __shared__ float csh[61];          // per-pair scales c_p/c_p0

  const int t = threadIdx.x;
  const long total2 = (long)N * 81 / 2;

  // ---- weight row 0 -> 61 SGPRs (inline, constant indices ONLY) ----
  float w0[61];
#pragma unroll
  for (int q = 0; q < 61; ++q) w0[q] = uniform_f32(mult[q]);

  if (t < 61) csh[t] = mult[t] * (1.0f / mult[0]);

  const float2* __restrict__ X1v = (const float2*)X1;
  const float2* __restrict__ X2v = (const float2*)X2;
  const long fbaseA = (long)blockIdx.x * (2 * NF2);  // chunk A float2 base
  const long fbaseB = fbaseA + NF2;                  // chunk B float2 base

  // ---- stage chunk A ----
#pragma unroll
  for (int j = 0; j < 5; ++j) {
    const int f = t + j * NT;
    if (f < NF2) {
      const long gf = fbaseA + f;
      float2 v1 = make_float2(0.f, 0.f), v2 = make_float2(0.f, 0.f);
      if (gf < total2) { v1 = X1v[gf]; v2 = X2v[gf]; }
      LDS_WRITE_PAIR(f, v1, v2);
    }
  }
  __syncthreads();  // A staged (vmcnt drain here is A's own loads)

  // ---- issue chunk-B global loads into registers (in flight during A) ----
  float2 bx1[5], bx2[5];  // constant-indexed only (unrolled) -> VGPRs
#pragma unroll
  for (int j = 0; j < 5; ++j) {
    bx1[j] = make_float2(0.f, 0.f);
    bx2[j] = make_float2(0.f, 0.f);
    const int f = t + j * NT;
    if (f < NF2) {
      const long gf = fbaseB + f;
      if (gf < total2) { bx1[j] = X1v[gf]; bx2[j] = X2v[gf]; }
    }
  }

  // ---- compute + store chunk A (B loads in flight; no barrier inside) ----
  const int mu = __builtin_amdgcn_readfirstlane(t >> 6);  // wave-uniform
  const int lane = t & 63;
  const int m1lo = (mu - 4 > 0) ? mu - 4 : 0;
  const int pbase = kPrefix[mu];
  const long nA = (long)blockIdx.x * (2 * NB) + lane;

  COMPUTE_AND_STORE(nA);

  __syncthreads();  // all waves done reading LDS A; vmcnt(0) drains B loads

  // ---- write chunk B registers -> LDS ----
#pragma unroll
  for (int j = 0; j < 5; ++j) {
    const int f = t + j * NT;
    if (f < NF2) LDS_WRITE_PAIR(f, bx1[j], bx2[j]);
  }
  __syncthreads();

  // ---- compute + store chunk B ----
  const long nB = nA + NB;
  COMPUTE_AND_STORE(nB);
}

extern "C" void kernel_launch(void* const* d_in, const int* in_sizes, int n_in,
                              void* d_out, int out_size, void* d_ws, size_t ws_size,
                              hipStream_t stream) {
  const float* X1 = (const float*)d_in[0];
  const float* X2 = (const float*)d_in[1];
  const float* mult = (const float*)d_in[6];
  float* out = (float*)d_out;

  const int N = in_sizes[0] / 81;
  const int blocks = (N + 2 * NB - 1) / (2 * NB);
  wigner_combine_kernel<<<blocks, NT, 0, stream>>>(X1, X2, mult, out, N);
}

// Round 15
// 103.103 us; speedup vs baseline: 2.0149x; 1.0084x over previous
//
#include <hip/hip_runtime.h>

// out[n, mu, mup] = sum_{(m1,m2)∈T(mu)} sum_{(m1p,m2p)∈T(mup)}
//     c_p*c_q * X1[n,m1,m1p] * X2[n,m2,m2p],   T(mu)={m1+m2==mu+4}
// Rank-1 weights: cs[p]*w0[q] = c_p*c_q, w0[q]=mult[q], cs[p]=mult[p]/mult[0].
//
// R15 = R10 (best, ~23us) with the staging path replaced by
// __builtin_amdgcn_global_load_lds width=16 (async DMA, no VGPR round-trip).
// Key: NO transpose needed — a verbatim linear copy of the global [n][81]
// layout is already conflict-free for compute: lane reads lds[lane*81 + c],
// stride 81 ≡ 17 mod 32 (odd) -> 2 lanes/bank = free (m136). The wave-
// uniform-base+lane*16 order global_load_lds REQUIRES is exactly this
// layout. Staging: ~5 wave-instrs/wave vs ~55 per-thread instrs in R10
// (magic-div + 10 loads + 20 ds_writes). Everything else R10-verbatim.
// HARD RULES (R6/R8/R11): w0[61] inline, const-indexed only, never
// passed/addressed. No runtime-indexed register arrays.

namespace {

struct QTab {
  int m1p[61];
  int m2p[61];
  int mup[61];
  constexpr QTab() : m1p{}, m2p{}, mup{} {
    int idx = 0;
    for (int mu = 0; mu < 9; ++mu)
      for (int a = 0; a < 9; ++a) {
        int b = mu + 4 - a;
        if (b >= 0 && b < 9) {
          m1p[idx] = a; m2p[idx] = b; mup[idx] = mu; ++idx;
        }
      }
  }
};
constexpr QTab QT{};

}  // namespace

// pairs per mu: [5,6,7,8,9,8,7,6,5]; prefix = first pair index of each mu
__constant__ __device__ int kPrefix[9] = {0, 5, 11, 18, 26, 35, 43, 50, 56};

__device__ __forceinline__ float uniform_f32(float v) {
  return __int_as_float(__builtin_amdgcn_readfirstlane(__float_as_int(v)));
}

typedef unsigned int u32;

// Async global->LDS DMA. Per-lane global src; LDS dest = uniform base +
// lane*SZ (SZ = 16 or 4 bytes). Counts in vmcnt; drained by __syncthreads.
__device__ __forceinline__ void glds16(const float* g, float* lds) {
  __builtin_amdgcn_global_load_lds(
      (const __attribute__((address_space(1))) u32*)g,
      (__attribute__((address_space(3))) u32*)(u32)(uintptr_t)lds, 16, 0, 0);
}
__device__ __forceinline__ void glds4(const float* g, float* lds) {
  __builtin_amdgcn_global_load_lds(
      (const __attribute__((address_space(1))) u32*)g,
      (__attribute__((address_space(3))) u32*)(u32)(uintptr_t)lds, 4, 0, 0);
}

#define NB 64            // n per block
#define NT 576           // threads = 9 waves (wave = mu, lane = n-local)
#define AD (NB * 81)     // 5184 dwords per array per block
#define CH 256           // dwords per x16 wave-chunk (64 lanes * 4 dw)
#define NCH 20           // full x16 chunks per array (20*256 = 5120)
#define TAILB 5120       // tail base (64 dwords, staged at width 4)

__global__ __launch_bounds__(NT)
void wigner_combine_kernel(const float* __restrict__ X1,
                           const float* __restrict__ X2,
                           const float* __restrict__ mult,
                           float* __restrict__ out, int N) {
  __shared__ __align__(16) float x1s[AD];  // 20736 B, linear [n][81]
  __shared__ __align__(16) float x2s[AD];  // 20736 B
  __shared__ float csh[61];                // per-pair scales c_p/c_p0

  const int t = threadIdx.x;
  const int w = t >> 6;      // wave id 0..8
  const int lane = t & 63;
  const long gbase = (long)blockIdx.x * AD;  // dword base of this block
  const long totaldw = (long)N * 81;

  // ---- weight row 0 -> 61 SGPRs (inline, constant indices ONLY) ----
  float w0[61];
#pragma unroll
  for (int q = 0; q < 61; ++q) w0[q] = uniform_f32(mult[q]);

  if (t < 61) csh[t] = mult[t] * (1.0f / mult[0]);

  // ---- stage: async linear DMA, both arrays. 40 x16 chunks + 2 x4 tails
  // distributed over 9 waves. Per-lane guard only binds in the last block.
#pragma unroll
  for (int k = 0; k < 5; ++k) {
    const int i = w + 9 * k;  // wave-uniform chunk id
    if (i < 2 * NCH) {
      const int cbase = (i < NCH ? i : i - NCH) * CH;
      const float* gsrc = (i < NCH ? X1 : X2) + gbase + cbase + lane * 4;
      float* ldst = (i < NCH ? x1s : x2s) + cbase;
      if (gbase + cbase + lane * 4 < totaldw) glds16(gsrc, ldst);
    }
  }
  if (w == 0) {
    if (gbase + TAILB + lane < totaldw)
      glds4(X1 + gbase + TAILB + lane, x1s + TAILB);
  } else if (w == 1) {
    if (gbase + TAILB + lane < totaldw)
      glds4(X2 + gbase + TAILB + lane, x2s + TAILB);
  }
  __syncthreads();  // vmcnt(0) drains the DMA

  // ---- compute: wave = mu, lane = local n (R10 verbatim, linear reads) ----
  const int mu = __builtin_amdgcn_readfirstlane(w);  // wave-uniform
  const int m1lo = (mu - 4 > 0) ? mu - 4 : 0;
  const int pbase = kPrefix[mu];

  const float* __restrict__ lx1 = x1s + lane * 81;
  const float* __restrict__ lx2 = x2s + lane * 81;

  float acc[9];
#pragma unroll
  for (int j = 0; j < 9; ++j) acc[j] = 0.0f;

#pragma unroll
  for (int m1 = 0; m1 < 9; ++m1) {
    const int m2 = mu + 4 - m1;      // wave-uniform scalar
    if (m2 < 0 || m2 > 8) continue;  // uniform guard (scalar branch)
    const int p = pbase + (m1 - m1lo);
    const float sp = csh[p];         // uniform ds_read broadcast, in-order

    float x1w[9], x2r[9];
#pragma unroll
    for (int j = 0; j < 9; ++j) x1w[j] = lx1[m1 * 9 + j] * sp;
#pragma unroll
    for (int j = 0; j < 9; ++j) x2r[j] = lx2[m2 * 9 + j];

#pragma unroll
    for (int q = 0; q < 61; ++q) {
      // weight = sp * w0[q] = c_p * c_q; w0 const-indexed (SGPRs)
      acc[QT.mup[q]] = fmaf(w0[q], x1w[QT.m1p[q]] * x2r[QT.m2p[q]],
                            acc[QT.mup[q]]);
    }
  }

  // ---- direct stores: out[n, mu, 0..8] (same-block waves cover all 81
  // components of each n -> L2 merges to full lines) ----
  const long n = (long)blockIdx.x * NB + lane;
  if (n < N) {
    float* __restrict__ op = out + n * 81 + mu * 9;
#pragma unroll
    for (int j = 0; j < 9; ++j) op[j] = acc[j];
  }
}

extern "C" void kernel_launch(void* const* d_in, const int* in_sizes, int n_in,
                              void* d_out, int out_size, void* d_ws, size_t ws_size,
                              hipStream_t stream) {
  const float* X1 = (const float*)d_in[0];
  const float* X2 = (const float*)d_in[1];
  const float* mult = (const float*)d_in[6];
  float* out = (float*)d_out;

  const int N = in_sizes[0] / 81;
  const int blocks = (N + NB - 1) / NB;
  wigner_combine_kernel<<<blocks, NT, 0, stream>>>(X1, X2, mult, out, N);
}